// Round 2
// baseline (5256.832 us; speedup 1.0000x reference)
//
#include <hip/hip_runtime.h>
#include <hip/hip_bf16.h>
#include <math.h>

#define N_NODES 10000
#define N_EDGES 160000
#define F 128
#define F4 512

static constexpr float TWO_PI_OVER_L = 6.283185307179586f / 10.0f;

__device__ __forceinline__ float silu_f(float x) { return x / (1.0f + __expf(-x)); }

__device__ __forceinline__ float bf2f(unsigned int u) {
    union { unsigned int i; float f; } x; x.i = u << 16; return x.f;
}
__device__ __forceinline__ unsigned int f2bf(float v) {
    unsigned int u = __float_as_uint(v);
    u += 0x7fff + ((u >> 16) & 1);           // round-to-nearest-even
    return u >> 16;
}

// layer1: 16 threads per row; thread c computes 8 outputs f0=c*8..+8 over K=128
__device__ __forceinline__ void layer1(const float xin[][F], float hout[][F],
                                       const float* __restrict__ w1,
                                       const float* __restrict__ b1,
                                       int e, int c)
{
    const int f0 = c * 8;
    float acc[8];
#pragma unroll
    for (int j = 0; j < 8; ++j) acc[j] = b1[f0 + j];
#pragma unroll 4
    for (int k = 0; k < F; ++k) {
        const float s = xin[e][k];
        const float4 wa = *(const float4*)&w1[k * F + f0];
        const float4 wb = *(const float4*)&w1[k * F + f0 + 4];
        acc[0] = fmaf(s, wa.x, acc[0]);
        acc[1] = fmaf(s, wa.y, acc[1]);
        acc[2] = fmaf(s, wa.z, acc[2]);
        acc[3] = fmaf(s, wa.w, acc[3]);
        acc[4] = fmaf(s, wb.x, acc[4]);
        acc[5] = fmaf(s, wb.y, acc[5]);
        acc[6] = fmaf(s, wb.z, acc[6]);
        acc[7] = fmaf(s, wb.w, acc[7]);
    }
#pragma unroll
    for (int j = 0; j < 8; ++j) hout[e][f0 + j] = silu_f(acc[j]);
}

// layer2: thread c accumulates 32 outputs f0=c*32..+32 over K=128
__device__ __forceinline__ void layer2_acc(const float hin[][F],
                                           const float* __restrict__ w2,
                                           const float* __restrict__ b2,
                                           int e, int c, float acc[32])
{
    const int f0 = c * 32;
#pragma unroll
    for (int j = 0; j < 32; ++j) acc[j] = b2[f0 + j];
    for (int k = 0; k < F; ++k) {
        const float s = hin[e][k];
        const float* wrow = &w2[k * F4 + f0];
#pragma unroll
        for (int j = 0; j < 32; j += 4) {
            const float4 w = *(const float4*)&wrow[j];
            acc[j + 0] = fmaf(s, w.x, acc[j + 0]);
            acc[j + 1] = fmaf(s, w.y, acc[j + 1]);
            acc[j + 2] = fmaf(s, w.z, acc[j + 2]);
            acc[j + 3] = fmaf(s, w.w, acc[j + 3]);
        }
    }
}

// ---------------- CSR build ----------------
__global__ void hist_kernel(const int* __restrict__ ei, int* __restrict__ counts) {
    const int e = blockIdx.x * 256 + threadIdx.x;
    atomicAdd(&counts[ei[N_EDGES + e]], 1);
}

#define SCAN_CHUNK 40   // 256*40 >= 10000
__global__ __launch_bounds__(256) void scan_kernel(const int* __restrict__ counts,
                                                   int* __restrict__ offsets,
                                                   int* __restrict__ cursor)
{
    __shared__ int part[256];
    const int t = threadIdx.x;
    const int base = t * SCAN_CHUNK;
    int s = 0;
    for (int i = 0; i < SCAN_CHUNK; ++i) {
        const int idx = base + i;
        if (idx < N_NODES) s += counts[idx];
    }
    part[t] = s;
    __syncthreads();
    for (int d = 1; d < 256; d <<= 1) {
        int v = 0;
        if (t >= d) v = part[t - d];
        __syncthreads();
        part[t] += v;
        __syncthreads();
    }
    int run = (t == 0) ? 0 : part[t - 1];
    for (int i = 0; i < SCAN_CHUNK; ++i) {
        const int idx = base + i;
        if (idx < N_NODES) {
            offsets[idx] = run;
            cursor[idx] = run;
            run += counts[idx];
        }
    }
    if (t == 255) offsets[N_NODES] = part[255];
}

__global__ void slot_kernel(const int* __restrict__ ei, int* __restrict__ cursor,
                            int* __restrict__ csr) {
    const int e = blockIdx.x * 256 + threadIdx.x;
    const int dst = ei[N_EDGES + e];
    const int s = atomicAdd(&cursor[dst], 1);
    csr[s] = e;
}

// ---------------- phi MLP per node (bf16 out) ----------------
__global__ __launch_bounds__(256) void node_mlp_kernel(
    const float* __restrict__ inv,
    const float* __restrict__ w1, const float* __restrict__ b1,
    const float* __restrict__ w2, const float* __restrict__ b2,
    unsigned short* __restrict__ phi)
{
    __shared__ float s_x[16][F];
    __shared__ float s_h[16][F];
    const int t = threadIdx.x;
    const int n0 = blockIdx.x * 16;
    const int e = t >> 4, c = t & 15;
    {
        const float4* xp = (const float4*)&inv[(n0 + e) * F + c * 8];
        *(float4*)&s_x[e][c * 8]     = xp[0];
        *(float4*)&s_x[e][c * 8 + 4] = xp[1];
    }
    __syncthreads();
    layer1(s_x, s_h, w1, b1, e, c);
    __syncthreads();
    float acc[32];
    layer2_acc(s_h, w2, b2, e, c, acc);
    unsigned int w[16];
#pragma unroll
    for (int p = 0; p < 16; ++p)
        w[p] = f2bf(acc[2 * p]) | (f2bf(acc[2 * p + 1]) << 16);
    uint4* o = (uint4*)(phi + (size_t)(n0 + e) * F4 + c * 32);
    o[0] = make_uint4(w[0], w[1], w[2], w[3]);
    o[1] = make_uint4(w[4], w[5], w[6], w[7]);
    o[2] = make_uint4(w[8], w[9], w[10], w[11]);
    o[3] = make_uint4(w[12], w[13], w[14], w[15]);
}

// ---------------- Path A: edge MLP -> m (bf16, edge order) ----------------
__global__ __launch_bounds__(256) void edge_mlp_kernel(
    const int* __restrict__ ei, const float* __restrict__ dist,
    const float* __restrict__ ww1, const float* __restrict__ wb1,
    const float* __restrict__ ww2, const float* __restrict__ wb2,
    const unsigned short* __restrict__ phi, unsigned short* __restrict__ m)
{
    __shared__ float s_pe[16][F];
    __shared__ float s_h[16][F];
    __shared__ int s_src[16];
    __shared__ float s_dist[16];
    const int t = threadIdx.x;
    const int e0 = blockIdx.x * 16;
    if (t < 16) {
        s_src[t]  = ei[e0 + t];
        s_dist[t] = dist[e0 + t];
    }
    __syncthreads();
    const int e = t >> 4, c = t & 15;
    {
        const float d = s_dist[e] * TWO_PI_OVER_L;
#pragma unroll
        for (int kk = 0; kk < 4; ++kk) {
            const int k = c * 4 + kk;
            float sv, cv;
            sincosf(d * (float)(k + 1), &sv, &cv);
            s_pe[e][2 * k]     = sv;
            s_pe[e][2 * k + 1] = cv;
        }
    }
    __syncthreads();
    layer1(s_pe, s_h, ww1, wb1, e, c);
    __syncthreads();
    float acc[32];
    layer2_acc(s_h, ww2, wb2, e, c, acc);

    const uint4* ph = (const uint4*)(phi + (size_t)s_src[e] * F4 + c * 32);
#pragma unroll
    for (int j4 = 0; j4 < 4; ++j4) {
        const uint4 u = ph[j4];
        acc[j4 * 8 + 0] *= bf2f(u.x & 0xffff);
        acc[j4 * 8 + 1] *= bf2f(u.x >> 16);
        acc[j4 * 8 + 2] *= bf2f(u.y & 0xffff);
        acc[j4 * 8 + 3] *= bf2f(u.y >> 16);
        acc[j4 * 8 + 4] *= bf2f(u.z & 0xffff);
        acc[j4 * 8 + 5] *= bf2f(u.z >> 16);
        acc[j4 * 8 + 6] *= bf2f(u.w & 0xffff);
        acc[j4 * 8 + 7] *= bf2f(u.w >> 16);
    }
    unsigned int w[16];
#pragma unroll
    for (int p = 0; p < 16; ++p)
        w[p] = f2bf(acc[2 * p]) | (f2bf(acc[2 * p + 1]) << 16);
    uint4* o = (uint4*)(m + (size_t)(e0 + e) * F4 + c * 32);
    o[0] = make_uint4(w[0], w[1], w[2], w[3]);
    o[1] = make_uint4(w[4], w[5], w[6], w[7]);
    o[2] = make_uint4(w[8], w[9], w[10], w[11]);
    o[3] = make_uint4(w[12], w[13], w[14], w[15]);
}

// ---------------- Path A: per-node gather (no atomics) ----------------
__global__ __launch_bounds__(256) void gather_kernel(
    const int* __restrict__ ei, const float* __restrict__ dirv,
    const int* __restrict__ offsets, const int* __restrict__ csr,
    const unsigned short* __restrict__ m,
    const float* __restrict__ inv, const float* __restrict__ equiv,
    float* __restrict__ out_v, float* __restrict__ out_s)
{
    const int t = threadIdx.x;
    const int n = blockIdx.x * 2 + (t >> 7);
    const int f = t & 127;
    const int beg = offsets[n], end = offsets[n + 1];
    float a0 = 0, a1 = 0, a2 = 0, w0 = 0, w1 = 0, w2 = 0, ss = 0;
    for (int si = beg; si < end; ++si) {
        const int e = csr[si];
        const int src = ei[e];
        const float d0 = dirv[e * 3 + 0];
        const float d1 = dirv[e * 3 + 1];
        const float d2 = dirv[e * 3 + 2];
        const unsigned short* mr = m + (size_t)e * F4;
        const float g   = bf2f(mr[f]);
        const float cg  = bf2f(mr[128 + f]);
        const float sed = bf2f(mr[256 + f]);
        const float sf  = bf2f(mr[384 + f]);
        const float* es = equiv + ((size_t)src * F + f) * 3;
        const float ax = es[0], ay = es[1], az = es[2];
        a0 = fmaf(g, ax, fmaf(sed, d0, a0));
        a1 = fmaf(g, ay, fmaf(sed, d1, a1));
        a2 = fmaf(g, az, fmaf(sed, d2, a2));
        w0 = fmaf(cg, d0, w0);
        w1 = fmaf(cg, d1, w1);
        w2 = fmaf(cg, d2, w2);
        ss = fmaf(sf, inv[(size_t)src * F + f], ss);
    }
    const float* eb = equiv + ((size_t)n * F + f) * 3;
    const float bx = eb[0], by = eb[1], bz = eb[2];
    const size_t ov = ((size_t)n * F + f) * 3;
    out_v[ov + 0] = bx + a0 + (w1 * bz - w2 * by);
    out_v[ov + 1] = by + a1 + (w2 * bx - w0 * bz);
    out_v[ov + 2] = bz + a2 + (w0 * by - w1 * bx);
    out_s[(size_t)n * F + f] = inv[(size_t)n * F + f] + ss;
}

// ---------------- Path B: node-centric fused recompute (small ws) ----------------
__global__ __launch_bounds__(256) void node_fused_kernel(
    const int* __restrict__ ei, const float* __restrict__ dist,
    const float* __restrict__ dirv,
    const float* __restrict__ inv, const float* __restrict__ equiv,
    const float* __restrict__ ww1, const float* __restrict__ wb1,
    const float* __restrict__ ww2, const float* __restrict__ wb2,
    const unsigned short* __restrict__ phi,
    const int* __restrict__ offsets, const int* __restrict__ csr,
    float* __restrict__ out_v, float* __restrict__ out_s)
{
    __shared__ float s_pe[16][F];
    __shared__ float s_h[16][F];
    __shared__ float s_m[16][F4];
    __shared__ int s_src[16];
    __shared__ float s_dist[16], s_dir[16][3];
    __shared__ float s_acc[F][7];
    const int n = blockIdx.x, t = threadIdx.x;
    const int beg = offsets[n], deg = offsets[n + 1] - beg;
    const int e = t >> 4, c = t & 15;
    const int f = t & 127, h = t >> 7;
    float a0 = 0, a1 = 0, a2 = 0, w0 = 0, w1 = 0, w2 = 0, ss = 0;
    for (int b0 = 0; b0 < deg; b0 += 16) {
        if (t < 16) {
            const int valid = (b0 + t) < deg;
            const int ee = valid ? csr[beg + b0 + t] : 0;
            s_src[t]  = valid ? ei[ee] : 0;
            s_dist[t] = valid ? dist[ee] : 0.f;
            s_dir[t][0] = valid ? dirv[ee * 3 + 0] : 0.f;
            s_dir[t][1] = valid ? dirv[ee * 3 + 1] : 0.f;
            s_dir[t][2] = valid ? dirv[ee * 3 + 2] : 0.f;
        }
        __syncthreads();
        {
            const float d = s_dist[e] * TWO_PI_OVER_L;
#pragma unroll
            for (int kk = 0; kk < 4; ++kk) {
                const int k = c * 4 + kk;
                float sv, cv;
                sincosf(d * (float)(k + 1), &sv, &cv);
                s_pe[e][2 * k]     = sv;
                s_pe[e][2 * k + 1] = cv;
            }
        }
        __syncthreads();
        layer1(s_pe, s_h, ww1, wb1, e, c);
        __syncthreads();
        float acc[32];
        layer2_acc(s_h, ww2, wb2, e, c, acc);
        const uint4* ph = (const uint4*)(phi + (size_t)s_src[e] * F4 + c * 32);
#pragma unroll
        for (int j4 = 0; j4 < 4; ++j4) {
            const uint4 u = ph[j4];
            acc[j4 * 8 + 0] *= bf2f(u.x & 0xffff);
            acc[j4 * 8 + 1] *= bf2f(u.x >> 16);
            acc[j4 * 8 + 2] *= bf2f(u.y & 0xffff);
            acc[j4 * 8 + 3] *= bf2f(u.y >> 16);
            acc[j4 * 8 + 4] *= bf2f(u.z & 0xffff);
            acc[j4 * 8 + 5] *= bf2f(u.z >> 16);
            acc[j4 * 8 + 6] *= bf2f(u.w & 0xffff);
            acc[j4 * 8 + 7] *= bf2f(u.w >> 16);
        }
#pragma unroll
        for (int j = 0; j < 32; ++j) s_m[e][c * 32 + j] = acc[j];
        __syncthreads();
#pragma unroll
        for (int rr = 0; rr < 8; ++rr) {
            const int r2 = h * 8 + rr;
            if ((b0 + r2) < deg) {
                const float g   = s_m[r2][f];
                const float cg  = s_m[r2][128 + f];
                const float sed = s_m[r2][256 + f];
                const float sf  = s_m[r2][384 + f];
                const int src = s_src[r2];
                const float d0 = s_dir[r2][0], d1 = s_dir[r2][1], d2 = s_dir[r2][2];
                const float* es = equiv + ((size_t)src * F + f) * 3;
                a0 = fmaf(g, es[0], fmaf(sed, d0, a0));
                a1 = fmaf(g, es[1], fmaf(sed, d1, a1));
                a2 = fmaf(g, es[2], fmaf(sed, d2, a2));
                w0 = fmaf(cg, d0, w0);
                w1 = fmaf(cg, d1, w1);
                w2 = fmaf(cg, d2, w2);
                ss = fmaf(sf, inv[(size_t)src * F + f], ss);
            }
        }
        __syncthreads();
    }
    if (h == 0) {
        s_acc[f][0] = a0; s_acc[f][1] = a1; s_acc[f][2] = a2;
        s_acc[f][3] = w0; s_acc[f][4] = w1; s_acc[f][5] = w2;
        s_acc[f][6] = ss;
    }
    __syncthreads();
    if (h == 1) {
        a0 += s_acc[f][0]; a1 += s_acc[f][1]; a2 += s_acc[f][2];
        w0 += s_acc[f][3]; w1 += s_acc[f][4]; w2 += s_acc[f][5];
        ss += s_acc[f][6];
        const float* eb = equiv + ((size_t)n * F + f) * 3;
        const float bx = eb[0], by = eb[1], bz = eb[2];
        const size_t ov = ((size_t)n * F + f) * 3;
        out_v[ov + 0] = bx + a0 + (w1 * bz - w2 * by);
        out_v[ov + 1] = by + a1 + (w2 * bx - w0 * bz);
        out_v[ov + 2] = bz + a2 + (w0 * by - w1 * bx);
        out_s[(size_t)n * F + f] = inv[(size_t)n * F + f] + ss;
    }
}

extern "C" void kernel_launch(void* const* d_in, const int* in_sizes, int n_in,
                              void* d_out, int out_size, void* d_ws, size_t ws_size,
                              hipStream_t stream)
{
    const int*   ei    = (const int*)d_in[0];
    const float* dist  = (const float*)d_in[1];
    const float* dirv  = (const float*)d_in[2];
    const float* inv   = (const float*)d_in[3];
    const float* equiv = (const float*)d_in[4];
    const float* pw1   = (const float*)d_in[5];
    const float* pb1   = (const float*)d_in[6];
    const float* pw2   = (const float*)d_in[7];
    const float* pb2   = (const float*)d_in[8];
    const float* ww1   = (const float*)d_in[9];
    const float* wb1   = (const float*)d_in[10];
    const float* ww2   = (const float*)d_in[11];
    const float* wb2   = (const float*)d_in[12];

    float* out_v = (float*)d_out;
    float* out_s = out_v + (size_t)N_NODES * F * 3;

    char* base = (char*)d_ws;
    size_t off = 0;
    auto take = [&](size_t bytes) -> void* {
        void* p = base + off;
        off = (off + bytes + 255) & ~(size_t)255;
        return p;
    };
    int* counts   = (int*)take((size_t)N_NODES * 4);
    int* offsets  = (int*)take((size_t)(N_NODES + 1) * 4);
    int* cursor   = (int*)take((size_t)N_NODES * 4);
    int* csr      = (int*)take((size_t)N_EDGES * 4);
    unsigned short* phi = (unsigned short*)take((size_t)N_NODES * F4 * 2);
    unsigned short* m   = (unsigned short*)take((size_t)N_EDGES * F4 * 2);
    const size_t a_need = off;
    const bool pathA = ws_size >= a_need;

    hipMemsetAsync(counts, 0, (size_t)N_NODES * 4, stream);
    hist_kernel<<<N_EDGES / 256, 256, 0, stream>>>(ei, counts);
    scan_kernel<<<1, 256, 0, stream>>>(counts, offsets, cursor);
    slot_kernel<<<N_EDGES / 256, 256, 0, stream>>>(ei, cursor, csr);
    node_mlp_kernel<<<N_NODES / 16, 256, 0, stream>>>(inv, pw1, pb1, pw2, pb2, phi);

    if (pathA) {
        edge_mlp_kernel<<<N_EDGES / 16, 256, 0, stream>>>(
            ei, dist, ww1, wb1, ww2, wb2, phi, m);
        gather_kernel<<<N_NODES / 2, 256, 0, stream>>>(
            ei, dirv, offsets, csr, m, inv, equiv, out_v, out_s);
    } else {
        node_fused_kernel<<<N_NODES, 256, 0, stream>>>(
            ei, dist, dirv, inv, equiv, ww1, wb1, ww2, wb2,
            phi, offsets, csr, out_v, out_s);
    }
}

// Round 3
// 281.567 us; speedup vs baseline: 18.6699x; 18.6699x over previous
//
#include <hip/hip_runtime.h>
#include <math.h>

#define N_NODES 10000
#define N_EDGES 160000
#define F 128
#define F4 512

static constexpr float TWO_PI_OVER_L = 6.283185307179586f / 10.0f;

typedef __attribute__((ext_vector_type(8))) short bf16x8;
typedef __attribute__((ext_vector_type(4))) float f32x4;

__device__ __forceinline__ float silu_f(float x) { return x / (1.0f + __expf(-x)); }

__device__ __forceinline__ float bf2f(unsigned int u) {
    union { unsigned int i; float f; } x; x.i = u << 16; return x.f;
}
__device__ __forceinline__ unsigned short f2bf(float v) {
    unsigned int u = __float_as_uint(v);
    u += 0x7fff + ((u >> 16) & 1);           // round-to-nearest-even
    return (unsigned short)(u >> 16);
}

// ---------------- weight packing: W[K x N] f32 -> fragment-major bf16 ----------------
// packed[(nt*4+kk)*64 + lane][j] = W[kk*32 + (lane>>4)*8 + j][nt*16 + (lane&15)]
__global__ void pack_kernel(const float* __restrict__ W, int N,
                            unsigned short* __restrict__ out)
{
    const int idx = blockIdx.x * 256 + threadIdx.x;
    const int total = (N >> 4) * 4 * 64;
    if (idx >= total) return;
    const int lane = idx & 63;
    const int frag = idx >> 6;
    const int kk = frag & 3, nt = frag >> 2;
    const int k0 = kk * 32 + ((lane >> 4) << 3);
    const int n  = (nt << 4) + (lane & 15);
    unsigned short tmp[8];
#pragma unroll
    for (int j = 0; j < 8; ++j) tmp[j] = f2bf(W[(size_t)(k0 + j) * N + n]);
    uint4* o = (uint4*)(out + (size_t)idx * 8);
    *o = *(const uint4*)tmp;
}

// ---------------- CSR build ----------------
__global__ void hist_kernel(const int* __restrict__ ei, int* __restrict__ counts) {
    const int e = blockIdx.x * 256 + threadIdx.x;
    atomicAdd(&counts[ei[N_EDGES + e]], 1);
}

#define SCAN_CHUNK 40
__global__ __launch_bounds__(256) void scan_kernel(const int* __restrict__ counts,
                                                   int* __restrict__ offsets,
                                                   int* __restrict__ cursor)
{
    __shared__ int part[256];
    const int t = threadIdx.x;
    const int base = t * SCAN_CHUNK;
    int s = 0;
    for (int i = 0; i < SCAN_CHUNK; ++i) {
        const int idx = base + i;
        if (idx < N_NODES) s += counts[idx];
    }
    part[t] = s;
    __syncthreads();
    for (int d = 1; d < 256; d <<= 1) {
        int v = 0;
        if (t >= d) v = part[t - d];
        __syncthreads();
        part[t] += v;
        __syncthreads();
    }
    int run = (t == 0) ? 0 : part[t - 1];
    for (int i = 0; i < SCAN_CHUNK; ++i) {
        const int idx = base + i;
        if (idx < N_NODES) {
            offsets[idx] = run;
            cursor[idx] = run;
            run += counts[idx];
        }
    }
    if (t == 255) offsets[N_NODES] = part[255];
}

__global__ void slot_kernel(const int* __restrict__ ei, int* __restrict__ cursor,
                            int* __restrict__ csr) {
    const int e = blockIdx.x * 256 + threadIdx.x;
    const int dst = ei[N_EDGES + e];
    const int s = atomicAdd(&cursor[dst], 1);
    csr[s] = e;
}

// ---------------- fused 2-layer MLP via MFMA ----------------
// MODE 0: node path. A = inv (f32 rows), out = phi = (silu(inv@pw1+b1))@pw2+b2
// MODE 1: edge path. A = PE(dist) generated in-register,
//                    out = m = ((silu(PE@ww1+b1))@ww2+b2) * phi[src]
template <int MODE>
__global__ __launch_bounds__(256) void mlp_gemm_kernel(
    const float* __restrict__ xin,            // MODE0: inv[N,F]; MODE1: dist[E]
    const int* __restrict__ ei,               // MODE1: src row of edge_index
    const unsigned short* __restrict__ w1p, const float* __restrict__ b1,
    const unsigned short* __restrict__ w2p, const float* __restrict__ b2,
    const unsigned short* __restrict__ phi,   // MODE1 only
    unsigned short* __restrict__ out, const int nrows)
{
    __shared__ char s_h[4][4096];             // per-wave 16x128 bf16, XOR-swizzled
    const int t = threadIdx.x;
    const int w = t >> 6, l = t & 63;
    const int rb = blockIdx.x * 64 + w * 16;  // wave's base row
    const int lr = l & 15;
    const int kb = (l >> 4) << 3;             // 0,8,16,24
    char* sh = s_h[w];

    // ---- A fragments (4 k-steps of 32) ----
    bf16x8 a[4];
    if (MODE == 0) {
        int row = rb + lr;
        if (row > nrows - 1) row = nrows - 1;
        const float* xr = xin + (size_t)row * F;
#pragma unroll
        for (int kk = 0; kk < 4; ++kk) {
            const float4 v0 = *(const float4*)(xr + kk * 32 + kb);
            const float4 v1 = *(const float4*)(xr + kk * 32 + kb + 4);
            bf16x8 av;
            av[0] = (short)f2bf(v0.x); av[1] = (short)f2bf(v0.y);
            av[2] = (short)f2bf(v0.z); av[3] = (short)f2bf(v0.w);
            av[4] = (short)f2bf(v1.x); av[5] = (short)f2bf(v1.y);
            av[6] = (short)f2bf(v1.z); av[7] = (short)f2bf(v1.w);
            a[kk] = av;
        }
    } else {
        const float d = xin[rb + lr] * TWO_PI_OVER_L;
#pragma unroll
        for (int kk = 0; kk < 4; ++kk) {
            const int q0 = (kk * 32 + kb) >> 1;   // 0-based rank index
            bf16x8 av;
#pragma unroll
            for (int i = 0; i < 4; ++i) {
                float sv, cv;
                sincosf(d * (float)(q0 + 1 + i), &sv, &cv);
                av[2 * i]     = (short)f2bf(sv);
                av[2 * i + 1] = (short)f2bf(cv);
            }
            a[kk] = av;
        }
    }

    const bf16x8* B1 = (const bf16x8*)w1p;
    const bf16x8* B2 = (const bf16x8*)w2p;

    // ---- GEMM1: H(16x128) = silu(A @ W1 + b1) -> swizzled LDS ----
#pragma unroll
    for (int nt = 0; nt < 8; ++nt) {
        const int n = nt * 16 + lr;
        const float bias = b1[n];
        f32x4 acc = { bias, bias, bias, bias };
#pragma unroll
        for (int kk = 0; kk < 4; ++kk)
            acc = __builtin_amdgcn_mfma_f32_16x16x32_bf16(
                a[kk], B1[(nt * 4 + kk) * 64 + l], acc, 0, 0, 0);
#pragma unroll
        for (int r = 0; r < 4; ++r) {
            const int row = (l >> 4) * 4 + r;
            const int byte = (row * 256 + n * 2) ^ ((row & 7) << 4);
            *(unsigned short*)(sh + byte) = f2bf(silu_f(acc[r]));
        }
    }

    // ---- A2 fragments from LDS (swizzled ds_read_b128) ----
    bf16x8 a2[4];
#pragma unroll
    for (int kk = 0; kk < 4; ++kk) {
        const int byte = (lr * 256 + (kk * 32 + kb) * 2) ^ ((lr & 7) << 4);
        a2[kk] = *(const bf16x8*)(sh + byte);
    }

    int srcs[4];
    if (MODE == 1) {
#pragma unroll
        for (int r = 0; r < 4; ++r) srcs[r] = ei[rb + (l >> 4) * 4 + r];
    }

    // ---- GEMM2: M(16x512) = H @ W2 + b2, fused epilogue ----
#pragma unroll 4
    for (int nt = 0; nt < 32; ++nt) {
        const int n = nt * 16 + lr;
        const float bias = b2[n];
        f32x4 acc = { bias, bias, bias, bias };
#pragma unroll
        for (int kk = 0; kk < 4; ++kk)
            acc = __builtin_amdgcn_mfma_f32_16x16x32_bf16(
                a2[kk], B2[(nt * 4 + kk) * 64 + l], acc, 0, 0, 0);
#pragma unroll
        for (int r = 0; r < 4; ++r) {
            const int row = (l >> 4) * 4 + r;
            const int grow = rb + row;
            float v = acc[r];
            if (MODE == 1) {
                v *= bf2f(phi[(size_t)srcs[r] * F4 + n]);
                out[(size_t)grow * F4 + n] = f2bf(v);
            } else {
                if (grow < nrows) out[(size_t)grow * F4 + n] = f2bf(v);
            }
        }
    }
}

// ---------------- per-node gather (no atomics) ----------------
__global__ __launch_bounds__(256) void gather_kernel(
    const int* __restrict__ ei, const float* __restrict__ dirv,
    const int* __restrict__ offsets, const int* __restrict__ csr,
    const unsigned short* __restrict__ m,
    const float* __restrict__ inv, const float* __restrict__ equiv,
    float* __restrict__ out_v, float* __restrict__ out_s)
{
    const int t = threadIdx.x;
    const int n = blockIdx.x * 2 + (t >> 7);
    const int f = t & 127;
    const int beg = offsets[n], end = offsets[n + 1];
    float a0 = 0, a1 = 0, a2 = 0, w0 = 0, w1 = 0, w2 = 0, ss = 0;
    for (int si = beg; si < end; ++si) {
        const int e = csr[si];
        const int src = ei[e];
        const float d0 = dirv[e * 3 + 0];
        const float d1 = dirv[e * 3 + 1];
        const float d2 = dirv[e * 3 + 2];
        const unsigned short* mr = m + (size_t)e * F4;
        const float g   = bf2f(mr[f]);
        const float cg  = bf2f(mr[128 + f]);
        const float sed = bf2f(mr[256 + f]);
        const float sf  = bf2f(mr[384 + f]);
        const float* es = equiv + ((size_t)src * F + f) * 3;
        const float ax = es[0], ay = es[1], az = es[2];
        a0 = fmaf(g, ax, fmaf(sed, d0, a0));
        a1 = fmaf(g, ay, fmaf(sed, d1, a1));
        a2 = fmaf(g, az, fmaf(sed, d2, a2));
        w0 = fmaf(cg, d0, w0);
        w1 = fmaf(cg, d1, w1);
        w2 = fmaf(cg, d2, w2);
        ss = fmaf(sf, inv[(size_t)src * F + f], ss);
    }
    const float* eb = equiv + ((size_t)n * F + f) * 3;
    const float bx = eb[0], by = eb[1], bz = eb[2];
    const size_t ov = ((size_t)n * F + f) * 3;
    out_v[ov + 0] = bx + a0 + (w1 * bz - w2 * by);
    out_v[ov + 1] = by + a1 + (w2 * bx - w0 * bz);
    out_v[ov + 2] = bz + a2 + (w0 * by - w1 * bx);
    out_s[(size_t)n * F + f] = inv[(size_t)n * F + f] + ss;
}

extern "C" void kernel_launch(void* const* d_in, const int* in_sizes, int n_in,
                              void* d_out, int out_size, void* d_ws, size_t ws_size,
                              hipStream_t stream)
{
    const int*   ei    = (const int*)d_in[0];
    const float* dist  = (const float*)d_in[1];
    const float* dirv  = (const float*)d_in[2];
    const float* inv   = (const float*)d_in[3];
    const float* equiv = (const float*)d_in[4];
    const float* pw1   = (const float*)d_in[5];
    const float* pb1   = (const float*)d_in[6];
    const float* pw2   = (const float*)d_in[7];
    const float* pb2   = (const float*)d_in[8];
    const float* ww1   = (const float*)d_in[9];
    const float* wb1   = (const float*)d_in[10];
    const float* ww2   = (const float*)d_in[11];
    const float* wb2   = (const float*)d_in[12];

    float* out_v = (float*)d_out;
    float* out_s = out_v + (size_t)N_NODES * F * 3;

    char* base = (char*)d_ws;
    size_t off = 0;
    auto take = [&](size_t bytes) -> void* {
        void* p = base + off;
        off = (off + bytes + 255) & ~(size_t)255;
        return p;
    };
    int* counts  = (int*)take((size_t)N_NODES * 4);
    int* offsets = (int*)take((size_t)(N_NODES + 1) * 4);
    int* cursor  = (int*)take((size_t)N_NODES * 4);
    int* csr     = (int*)take((size_t)N_EDGES * 4);
    unsigned short* phi  = (unsigned short*)take((size_t)N_NODES * F4 * 2);
    unsigned short* ww1p = (unsigned short*)take((size_t)F * F * 2);
    unsigned short* ww2p = (unsigned short*)take((size_t)F * F4 * 2);
    unsigned short* pw1p = (unsigned short*)take((size_t)F * F * 2);
    unsigned short* pw2p = (unsigned short*)take((size_t)F * F4 * 2);
    unsigned short* m    = (unsigned short*)take((size_t)N_EDGES * F4 * 2);
    (void)ws_size;

    hipMemsetAsync(counts, 0, (size_t)N_NODES * 4, stream);
    hist_kernel<<<N_EDGES / 256, 256, 0, stream>>>(ei, counts);
    scan_kernel<<<1, 256, 0, stream>>>(counts, offsets, cursor);
    slot_kernel<<<N_EDGES / 256, 256, 0, stream>>>(ei, cursor, csr);

    pack_kernel<<<8, 256, 0, stream>>>(ww1, F, ww1p);
    pack_kernel<<<32, 256, 0, stream>>>(ww2, F4, ww2p);
    pack_kernel<<<8, 256, 0, stream>>>(pw1, F, pw1p);
    pack_kernel<<<32, 256, 0, stream>>>(pw2, F4, pw2p);

    mlp_gemm_kernel<0><<<(N_NODES + 63) / 64, 256, 0, stream>>>(
        inv, nullptr, pw1p, pb1, pw2p, pb2, nullptr, phi, N_NODES);
    mlp_gemm_kernel<1><<<N_EDGES / 64, 256, 0, stream>>>(
        dist, ei, ww1p, wb1, ww2p, wb2, phi, m, N_EDGES);

    gather_kernel<<<N_NODES / 2, 256, 0, stream>>>(
        ei, dirv, offsets, csr, m, inv, equiv, out_v, out_s);
}